// Round 1
// baseline (560.851 us; speedup 1.0000x reference)
//
#include <hip/hip_runtime.h>
#include <hip/hip_bf16.h>
#include <math.h>

// Problem constants (fixed by setup_inputs)
#define BB 16
#define NN 1024
#define DD 1024
#define PP 256
#define KK 16
#define MROWS (BB*NN)   // 16384

// ---------------------------------------------------------------------------
// Build Wcat (256 x 512): [:,0:256] = W1 - W2 ; [:,256:512] = W2
// where W1 = W_edge[0:256,:], W2 = W_edge[256:512,:]
// ---------------------------------------------------------------------------
__global__ __launch_bounds__(256) void build_wcat_kernel(
    const float* __restrict__ We, float* __restrict__ Wc)
{
    int i = blockIdx.x * 256 + threadIdx.x;   // 0 .. 256*256-1
    int d = i >> 8, p = i & 255;
    float w1 = We[d * 256 + p];
    float w2 = We[(d + 256) * 256 + p];
    Wc[d * 512 + p]       = w1 - w2;
    Wc[d * 512 + 256 + p] = w2;
}

// ---------------------------------------------------------------------------
// Generic fp32 GEMM: C = op(A[MxKd] @ B[KdxN] (+bias) (+src)) with opt ReLU
// 64x64 tile, BK=16, 256 threads, 4x4 per-thread microtile.
// ---------------------------------------------------------------------------
template<bool RELU, bool BIAS, bool ADDSRC>
__global__ __launch_bounds__(256) void gemm_f32_kernel(
    const float* __restrict__ A, const float* __restrict__ B,
    const float* __restrict__ bias, const float* __restrict__ src,
    float* __restrict__ C, int M, int N, int Kd)
{
    __shared__ float As[16][68];
    __shared__ float Bs[16][68];

    const int tid = threadIdx.x;
    const int tx = tid & 15, ty = tid >> 4;
    const int row0 = blockIdx.y * 64, col0 = blockIdx.x * 64;

    // A staging: thread loads A[row0 + tid>>2][k0 + (tid&3)*4 .. +3]
    const int arow  = tid >> 2, acol4 = (tid & 3) * 4;
    // B staging: thread loads B[k0 + tid>>4][col0 + (tid&15)*4 .. +3]
    const int brow  = tid >> 4, bcol4 = (tid & 15) * 4;

    float acc[4][4] = {};

    for (int k0 = 0; k0 < Kd; k0 += 16) {
        float4 av = *reinterpret_cast<const float4*>(
            &A[(long)(row0 + arow) * Kd + k0 + acol4]);
        float4 bv = *reinterpret_cast<const float4*>(
            &B[(long)(k0 + brow) * N + col0 + bcol4]);
        __syncthreads();   // previous iteration's LDS reads done
        As[acol4 + 0][arow] = av.x;
        As[acol4 + 1][arow] = av.y;
        As[acol4 + 2][arow] = av.z;
        As[acol4 + 3][arow] = av.w;
        *reinterpret_cast<float4*>(&Bs[brow][bcol4]) = bv;
        __syncthreads();
        #pragma unroll
        for (int k = 0; k < 16; ++k) {
            float4 a4 = *reinterpret_cast<const float4*>(&As[k][ty * 4]);
            float4 b4 = *reinterpret_cast<const float4*>(&Bs[k][tx * 4]);
            acc[0][0] += a4.x * b4.x; acc[0][1] += a4.x * b4.y;
            acc[0][2] += a4.x * b4.z; acc[0][3] += a4.x * b4.w;
            acc[1][0] += a4.y * b4.x; acc[1][1] += a4.y * b4.y;
            acc[1][2] += a4.y * b4.z; acc[1][3] += a4.y * b4.w;
            acc[2][0] += a4.z * b4.x; acc[2][1] += a4.z * b4.y;
            acc[2][2] += a4.z * b4.z; acc[2][3] += a4.z * b4.w;
            acc[3][0] += a4.w * b4.x; acc[3][1] += a4.w * b4.y;
            acc[3][2] += a4.w * b4.z; acc[3][3] += a4.w * b4.w;
        }
    }

    #pragma unroll
    for (int i = 0; i < 4; ++i) {
        const int r = row0 + ty * 4 + i;
        const int c = col0 + tx * 4;
        float4 v = make_float4(acc[i][0], acc[i][1], acc[i][2], acc[i][3]);
        if (BIAS) {
            v.x += bias[c + 0]; v.y += bias[c + 1];
            v.z += bias[c + 2]; v.w += bias[c + 3];
        }
        if (ADDSRC) {
            float4 s4 = *reinterpret_cast<const float4*>(&src[(long)r * N + c]);
            v.x += s4.x; v.y += s4.y; v.z += s4.z; v.w += s4.w;
        }
        if (RELU) {
            v.x = fmaxf(v.x, 0.f); v.y = fmaxf(v.y, 0.f);
            v.z = fmaxf(v.z, 0.f); v.w = fmaxf(v.w, 0.f);
        }
        *reinterpret_cast<float4*>(&C[(long)r * N + c]) = v;
    }
}

// ---------------------------------------------------------------------------
// KNN: per (b,n) row, indices of the 16 smallest d2 (set semantics, ties ->
// lower index, matches lax.top_k set). One wave per row, 4 rows per block.
// ---------------------------------------------------------------------------
__global__ __launch_bounds__(256) void knn_kernel(
    const float* __restrict__ points, int* __restrict__ idx_out)
{
    __shared__ float px[NN], py[NN], pz[NN], psq[NN];
    const int b = blockIdx.x;
    const int tid = threadIdx.x;
    const float* P = points + (long)b * NN * 3;
    for (int i = tid; i < NN; i += 256) {
        float x = P[i * 3 + 0], y = P[i * 3 + 1], z = P[i * 3 + 2];
        px[i] = x; py[i] = y; pz[i] = z;
        psq[i] = x * x + y * y + z * z;
    }
    __syncthreads();

    const int wave = tid >> 6, lane = tid & 63;
    const int n = blockIdx.y * 4 + wave;
    const float xn = px[n], yn = py[n], zn = pz[n], sqn = psq[n];

    float d[16];
    #pragma unroll
    for (int j = 0; j < 16; ++j) {
        int m = lane + 64 * j;
        float dot = xn * px[m] + yn * py[m] + zn * pz[m];
        d[j] = (sqn + psq[m]) - 2.0f * dot;
    }

    int* out = idx_out + ((long)b * NN + n) * KK;
    for (int it = 0; it < KK; ++it) {
        float bv = d[0]; int bj = 0;
        #pragma unroll
        for (int j = 1; j < 16; ++j)
            if (d[j] < bv) { bv = d[j]; bj = j; }
        int bm = lane + 64 * bj;
        #pragma unroll
        for (int off = 1; off < 64; off <<= 1) {
            float ov = __shfl_xor(bv, off);
            int   om = __shfl_xor(bm, off);
            if (ov < bv || (ov == bv && om < bm)) { bv = ov; bm = om; }
        }
        if ((bm & 63) == lane) d[bm >> 6] = 3.0e38f;
        if (lane == 0) out[it] = bm;
    }
}

// ---------------------------------------------------------------------------
// Gather + max/min over K neighbors + BN + ReLU  -> local (MROWS x 256)
// local[p] = relu( s*(c + be + (s>=0 ? max_k n : min_k n)) + t )
// ---------------------------------------------------------------------------
__global__ __launch_bounds__(256) void edge_max_kernel(
    const float* __restrict__ cn,    // MROWS x 512: [c_term | n_term]
    const int*   __restrict__ idx,   // MROWS x 16 (per-batch indices)
    const float* __restrict__ b_edge,
    const float* __restrict__ gamma, const float* __restrict__ beta,
    const float* __restrict__ mean,  const float* __restrict__ var,
    float* __restrict__ local)
{
    const long row = blockIdx.x;          // 0..MROWS-1
    const int  p   = threadIdx.x;         // 0..255
    const long bbase = (row >> 10) << 10; // batch start row

    __shared__ int sidx[KK];
    if (p < KK) sidx[p] = idx[row * KK + p];
    __syncthreads();

    float mx = -3.0e38f, mn = 3.0e38f;
    #pragma unroll
    for (int k = 0; k < KK; ++k) {
        float v = cn[(bbase + sidx[k]) * 512 + 256 + p];
        mx = fmaxf(mx, v);
        mn = fminf(mn, v);
    }
    float c = cn[row * 512 + p];
    float s = gamma[p] * rsqrtf(var[p] + 1e-5f);
    float t = beta[p] - mean[p] * s;
    float nsel = (s >= 0.f) ? mx : mn;
    local[row * 256 + p] = fmaxf(0.f, s * (c + b_edge[p] + nsel) + t);
}

// ---------------------------------------------------------------------------
extern "C" void kernel_launch(void* const* d_in, const int* in_sizes, int n_in,
                              void* d_out, int out_size, void* d_ws, size_t ws_size,
                              hipStream_t stream)
{
    const float* points   = (const float*)d_in[0];
    const float* features = (const float*)d_in[1];
    const float* W_down   = (const float*)d_in[2];
    const float* b_down   = (const float*)d_in[3];
    const float* W_edge   = (const float*)d_in[4];
    const float* b_edge   = (const float*)d_in[5];
    const float* bn_gamma = (const float*)d_in[6];
    const float* bn_beta  = (const float*)d_in[7];
    const float* bn_mean  = (const float*)d_in[8];
    const float* bn_var   = (const float*)d_in[9];
    const float* W_up     = (const float*)d_in[10];
    const float* b_up     = (const float*)d_in[11];
    float* out = (float*)d_out;

    float* ws = (float*)d_ws;
    float* feats_low = ws;                          // MROWS*256  = 4,194,304 f
    float* cn        = feats_low + (long)MROWS*256; // MROWS*512  = 8,388,608 f
    float* Wc        = cn + (long)MROWS*512;        // 256*512    = 131,072 f
    int*   nidx      = (int*)(Wc + 256*512);        // MROWS*16   = 262,144 i
    float* local     = feats_low;                   // reuse (feats_low dead after GEMM2)

    // 1. Wcat
    build_wcat_kernel<<<256, 256, 0, stream>>>(W_edge, Wc);

    // 2. feats_low = relu(features @ W_down + b_down)   (16384x1024 @ 1024x256)
    gemm_f32_kernel<true, true, false><<<dim3(PP/64, MROWS/64), 256, 0, stream>>>(
        features, W_down, b_down, nullptr, feats_low, MROWS, PP, DD);

    // 3. knn indices
    knn_kernel<<<dim3(BB, NN/4), 256, 0, stream>>>(points, nidx);

    // 4. cn = feats_low @ Wcat    (16384x256 @ 256x512)
    gemm_f32_kernel<false, false, false><<<dim3(512/64, MROWS/64), 256, 0, stream>>>(
        feats_low, Wc, nullptr, nullptr, cn, MROWS, 512, PP);

    // 5. gather-max + BN + relu -> local
    edge_max_kernel<<<MROWS, 256, 0, stream>>>(
        cn, nidx, b_edge, bn_gamma, bn_beta, bn_mean, bn_var, local);

    // 6. out = features + local @ W_up + b_up   (16384x256 @ 256x1024)
    gemm_f32_kernel<false, true, true><<<dim3(DD/64, MROWS/64), 256, 0, stream>>>(
        local, W_up, b_up, features, out, MROWS, DD, PP);
}

// Round 2
// 287.274 us; speedup vs baseline: 1.9523x; 1.9523x over previous
//
#include <hip/hip_runtime.h>
#include <hip/hip_bf16.h>
#include <math.h>

// Problem constants (fixed by setup_inputs)
#define BB 16
#define NN 1024
#define DD 1024
#define PP 256
#define KK 16
#define MROWS (BB*NN)   // 16384

typedef short bf16x8 __attribute__((ext_vector_type(8)));
typedef float f32x4  __attribute__((ext_vector_type(4)));

// ---------------------------------------------------------------------------
// async 16B global -> LDS (wave-uniform LDS base + lane*16)
// ---------------------------------------------------------------------------
__device__ __forceinline__ void async_copy16(const void* g, void* l) {
    __builtin_amdgcn_global_load_lds(
        (const __attribute__((address_space(1))) void*)g,
        (__attribute__((address_space(3))) void*)l, 16, 0, 0);
}

// ---------------------------------------------------------------------------
// Prep kernels: weight transposes to [N][K] bf16, features fp32 -> bf16
// ---------------------------------------------------------------------------
__global__ __launch_bounds__(256) void convert_bf16_kernel(
    const float* __restrict__ in, __hip_bfloat16* __restrict__ out)
{
    int i = blockIdx.x * 256 + threadIdx.x;   // one float4 per thread
    float4 v = reinterpret_cast<const float4*>(in)[i];
    __hip_bfloat16 h0 = __float2bfloat16(v.x), h1 = __float2bfloat16(v.y);
    __hip_bfloat16 h2 = __float2bfloat16(v.z), h3 = __float2bfloat16(v.w);
    ushort4 o;
    o.x = *reinterpret_cast<unsigned short*>(&h0);
    o.y = *reinterpret_cast<unsigned short*>(&h1);
    o.z = *reinterpret_cast<unsigned short*>(&h2);
    o.w = *reinterpret_cast<unsigned short*>(&h3);
    reinterpret_cast<ushort4*>(out)[i] = o;
}

__global__ __launch_bounds__(256) void prep_wdt_kernel(
    const float* __restrict__ Wd, __hip_bfloat16* __restrict__ Wdt)
{
    int i = blockIdx.x * 256 + threadIdx.x;   // over 256*1024
    int p = i >> 10, d = i & 1023;
    Wdt[i] = __float2bfloat16(Wd[d * 256 + p]);
}

__global__ __launch_bounds__(256) void prep_wct_kernel(
    const float* __restrict__ We, __hip_bfloat16* __restrict__ Wct)
{
    int i = blockIdx.x * 256 + threadIdx.x;   // over 512*256
    int n = i >> 8, d = i & 255;
    float v;
    if (n < 256) v = We[d * 256 + n] - We[(256 + d) * 256 + n];  // W1-W2 (^T)
    else         v = We[(256 + d) * 256 + (n - 256)];            // W2   (^T)
    Wct[i] = __float2bfloat16(v);
}

__global__ __launch_bounds__(256) void prep_wut_kernel(
    const float* __restrict__ Wu, __hip_bfloat16* __restrict__ Wut)
{
    int i = blockIdx.x * 256 + threadIdx.x;   // over 1024*256
    int dd = i >> 8, p = i & 255;
    Wut[i] = __float2bfloat16(Wu[p * 1024 + dd]);
}

// ---------------------------------------------------------------------------
// MFMA bf16 GEMM: C = op(A[MxK] @ Bt[NxK]^T (+bias) (+src))
// 128x128 tile, BK=32, 4 waves (2x2), each wave 64x64 = 4x4 frags of 16x16.
// A,B staged via global_load_lds width 16 into linear LDS. fp32 accumulate.
// ---------------------------------------------------------------------------
template<bool RELU, bool BIAS, bool ADDSRC, bool OUTBF16>
__global__ __launch_bounds__(256) void gemm_mfma_kernel(
    const __hip_bfloat16* __restrict__ A,    // [M][K]
    const __hip_bfloat16* __restrict__ Bt,   // [N][K]  (B transposed)
    const float* __restrict__ bias,          // [N] or null
    const float* __restrict__ src,           // [M][N] fp32 or null
    void* __restrict__ Cout,                 // bf16 or fp32 [M][N]
    int M, int N, int K)
{
    __shared__ __align__(16) __hip_bfloat16 As[128 * 32];
    __shared__ __align__(16) __hip_bfloat16 Bs[128 * 32];

    const int tid  = threadIdx.x;
    const int lane = tid & 63;
    const int wave = tid >> 6;              // 0..3
    const int wr = wave >> 1, wc = wave & 1;
    const int row0 = blockIdx.y * 128;
    const int col0 = blockIdx.x * 128;

    const int g  = lane >> 4;               // k-group 0..3
    const int lr = lane & 15;

    // staging geometry: chunk c covers LDS bytes [c*1024, c*1024+1024)
    // lane writes 16B at c*1024 + lane*16 -> row = c*16 + lane/4, col = (lane&3)*8
    const int srow = (lane >> 2);
    const int scol = (lane & 3) * 8;

    f32x4 acc[4][4];
    #pragma unroll
    for (int m = 0; m < 4; ++m)
        #pragma unroll
        for (int n = 0; n < 4; ++n)
            acc[m][n] = (f32x4){0.f, 0.f, 0.f, 0.f};

    for (int k0 = 0; k0 < K; k0 += 32) {
        __syncthreads();   // prior iter's LDS reads complete before overwrite
        #pragma unroll
        for (int r = 0; r < 2; ++r) {
            const int c = r * 4 + wave;                 // 0..7, wave-uniform
            const int arow = c * 16 + srow;
            async_copy16(A  + (row0 + arow) * (long)K + k0 + scol, As + c * 512);
            async_copy16(Bt + (col0 + arow) * (long)K + k0 + scol, Bs + c * 512);
        }
        __syncthreads();   // drains vmcnt(0): staged data visible

        bf16x8 af[4], bfr[4];
        #pragma unroll
        for (int m = 0; m < 4; ++m)
            af[m] = *reinterpret_cast<const bf16x8*>(
                &As[(wr * 64 + m * 16 + lr) * 32 + g * 8]);
        #pragma unroll
        for (int n = 0; n < 4; ++n)
            bfr[n] = *reinterpret_cast<const bf16x8*>(
                &Bs[(wc * 64 + n * 16 + lr) * 32 + g * 8]);
        #pragma unroll
        for (int m = 0; m < 4; ++m)
            #pragma unroll
            for (int n = 0; n < 4; ++n)
                acc[m][n] = __builtin_amdgcn_mfma_f32_16x16x32_bf16(
                    af[m], bfr[n], acc[m][n], 0, 0, 0);
    }

    // epilogue: C/D layout col=lane&15, row=(lane>>4)*4+j   [m89-verified]
    const int orow = row0 + wr * 64;
    const int ocol = col0 + wc * 64;
    #pragma unroll
    for (int m = 0; m < 4; ++m) {
        #pragma unroll
        for (int n = 0; n < 4; ++n) {
            const int gc = ocol + n * 16 + lr;
            const float bv = BIAS ? bias[gc] : 0.f;
            #pragma unroll
            for (int j = 0; j < 4; ++j) {
                const int gr = orow + m * 16 + g * 4 + j;
                float v = acc[m][n][j] + bv;
                if (ADDSRC) v += src[(long)gr * N + gc];
                if (RELU)   v = fmaxf(v, 0.f);
                if (OUTBF16)
                    reinterpret_cast<__hip_bfloat16*>(Cout)[(long)gr * N + gc] =
                        __float2bfloat16(v);
                else
                    reinterpret_cast<float*>(Cout)[(long)gr * N + gc] = v;
            }
        }
    }
}

// ---------------------------------------------------------------------------
// KNN (unchanged, fp32 — identical neighbor sets to round 1)
// ---------------------------------------------------------------------------
__global__ __launch_bounds__(256) void knn_kernel(
    const float* __restrict__ points, int* __restrict__ idx_out)
{
    __shared__ float px[NN], py[NN], pz[NN], psq[NN];
    const int b = blockIdx.x;
    const int tid = threadIdx.x;
    const float* P = points + (long)b * NN * 3;
    for (int i = tid; i < NN; i += 256) {
        float x = P[i * 3 + 0], y = P[i * 3 + 1], z = P[i * 3 + 2];
        px[i] = x; py[i] = y; pz[i] = z;
        psq[i] = x * x + y * y + z * z;
    }
    __syncthreads();

    const int wave = tid >> 6, lane = tid & 63;
    const int n = blockIdx.y * 4 + wave;
    const float xn = px[n], yn = py[n], zn = pz[n], sqn = psq[n];

    float d[16];
    #pragma unroll
    for (int j = 0; j < 16; ++j) {
        int m = lane + 64 * j;
        float dot = xn * px[m] + yn * py[m] + zn * pz[m];
        d[j] = (sqn + psq[m]) - 2.0f * dot;
    }

    int* out = idx_out + ((long)b * NN + n) * KK;
    for (int it = 0; it < KK; ++it) {
        float bv = d[0]; int bj = 0;
        #pragma unroll
        for (int j = 1; j < 16; ++j)
            if (d[j] < bv) { bv = d[j]; bj = j; }
        int bm = lane + 64 * bj;
        #pragma unroll
        for (int off = 1; off < 64; off <<= 1) {
            float ov = __shfl_xor(bv, off);
            int   om = __shfl_xor(bm, off);
            if (ov < bv || (ov == bv && om < bm)) { bv = ov; bm = om; }
        }
        if ((bm & 63) == lane) d[bm >> 6] = 3.0e38f;
        if (lane == 0) out[it] = bm;
    }
}

// ---------------------------------------------------------------------------
// Gather + max/min over K + BN + ReLU -> local (bf16)
// local[p] = relu( s*(c + be + (s>=0 ? max_k n : min_k n)) + t )
// ---------------------------------------------------------------------------
__global__ __launch_bounds__(256) void edge_max_kernel(
    const __hip_bfloat16* __restrict__ cn,   // MROWS x 512 bf16: [c | n]
    const int*   __restrict__ idx,           // MROWS x 16
    const float* __restrict__ b_edge,
    const float* __restrict__ gamma, const float* __restrict__ beta,
    const float* __restrict__ mean,  const float* __restrict__ var,
    __hip_bfloat16* __restrict__ local)
{
    const long row = blockIdx.x;
    const int  p   = threadIdx.x;
    const long bbase = (row >> 10) << 10;

    __shared__ int sidx[KK];
    if (p < KK) sidx[p] = idx[row * KK + p];
    __syncthreads();

    float mx = -3.0e38f, mn = 3.0e38f;
    #pragma unroll
    for (int k = 0; k < KK; ++k) {
        float v = __bfloat162float(cn[(bbase + sidx[k]) * 512 + 256 + p]);
        mx = fmaxf(mx, v);
        mn = fminf(mn, v);
    }
    float c = __bfloat162float(cn[row * 512 + p]);
    float s = gamma[p] * rsqrtf(var[p] + 1e-5f);
    float t = beta[p] - mean[p] * s;
    float nsel = (s >= 0.f) ? mx : mn;
    local[row * 256 + p] = __float2bfloat16(fmaxf(0.f, s * (c + b_edge[p] + nsel) + t));
}

// ---------------------------------------------------------------------------
extern "C" void kernel_launch(void* const* d_in, const int* in_sizes, int n_in,
                              void* d_out, int out_size, void* d_ws, size_t ws_size,
                              hipStream_t stream)
{
    const float* points   = (const float*)d_in[0];
    const float* features = (const float*)d_in[1];
    const float* W_down   = (const float*)d_in[2];
    const float* b_down   = (const float*)d_in[3];
    const float* W_edge   = (const float*)d_in[4];
    const float* b_edge   = (const float*)d_in[5];
    const float* bn_gamma = (const float*)d_in[6];
    const float* bn_beta  = (const float*)d_in[7];
    const float* bn_mean  = (const float*)d_in[8];
    const float* bn_var   = (const float*)d_in[9];
    const float* W_up     = (const float*)d_in[10];
    const float* b_up     = (const float*)d_in[11];
    float* out = (float*)d_out;

    // workspace layout (region0 reused: featuresh dead after GEMM1)
    char* w = (char*)d_ws;
    __hip_bfloat16* featuresh = (__hip_bfloat16*)w;                   // 32MB [0,32M)
    __hip_bfloat16* cn        = (__hip_bfloat16*)w;                   // 16MB [0,16M)
    __hip_bfloat16* local     = (__hip_bfloat16*)(w + (16ul << 20));  //  8MB [16,24M)
    __hip_bfloat16* feats_low = (__hip_bfloat16*)(w + (32ul << 20));  //  8MB [32,40M)
    char* wtail = w + (40ul << 20);
    __hip_bfloat16* Wdt = (__hip_bfloat16*)wtail;                     // 512KB
    __hip_bfloat16* Wct = (__hip_bfloat16*)(wtail + 524288);          // 256KB
    __hip_bfloat16* Wut = (__hip_bfloat16*)(wtail + 524288 + 262144); // 512KB
    int* nidx = (int*)(wtail + 524288 + 262144 + 524288);             // 1MB

    // prep
    convert_bf16_kernel<<<MROWS * DD / 4 / 256, 256, 0, stream>>>(features, featuresh);
    prep_wdt_kernel<<<1024, 256, 0, stream>>>(W_down, Wdt);
    prep_wct_kernel<<<512, 256, 0, stream>>>(W_edge, Wct);
    prep_wut_kernel<<<1024, 256, 0, stream>>>(W_up, Wut);
    knn_kernel<<<dim3(BB, NN / 4), 256, 0, stream>>>(points, nidx);

    // GEMM1: feats_low = relu(features @ W_down + b_down)  [16384x256, K=1024]
    gemm_mfma_kernel<true, true, false, true><<<dim3(2, 128), 256, 0, stream>>>(
        featuresh, Wdt, b_down, nullptr, feats_low, MROWS, 256, 1024);

    // GEMM2: cn = feats_low @ Wcat  [16384x512, K=256]
    gemm_mfma_kernel<false, false, false, true><<<dim3(4, 128), 256, 0, stream>>>(
        feats_low, Wct, nullptr, nullptr, cn, MROWS, 512, 256);

    // gather-max + BN + relu -> local (bf16)
    edge_max_kernel<<<MROWS, 256, 0, stream>>>(
        cn, nidx, b_edge, bn_gamma, bn_beta, bn_mean, bn_var, local);

    // GEMM3: out = features + local @ W_up + b_up  [16384x1024, K=256]
    gemm_mfma_kernel<false, true, true, false><<<dim3(8, 128), 256, 0, stream>>>(
        local, Wut, b_up, features, out, MROWS, 1024, 256);
}

// Round 4
// 247.406 us; speedup vs baseline: 2.2669x; 1.1611x over previous
//
#include <hip/hip_runtime.h>
#include <hip/hip_bf16.h>
#include <math.h>

// Problem constants (fixed by setup_inputs)
#define BB 16
#define NN 1024
#define DD 1024
#define PP 256
#define KK 16
#define MROWS (BB*NN)   // 16384

typedef short bf16x8 __attribute__((ext_vector_type(8)));
typedef float f32x4  __attribute__((ext_vector_type(4)));
typedef unsigned short u16x8 __attribute__((ext_vector_type(8)));

// ---------------------------------------------------------------------------
// async 16B global -> LDS (wave-uniform LDS base + lane*16)
// ---------------------------------------------------------------------------
__device__ __forceinline__ void async_copy16(const void* g, void* l) {
    __builtin_amdgcn_global_load_lds(
        (const __attribute__((address_space(1))) void*)g,
        (__attribute__((address_space(3))) void*)l, 16, 0, 0);
}

// ---------------------------------------------------------------------------
// Fused weight prep: Wdt = W_down^T (bf16), Wct = Wcat^T (bf16), Wut = W_up^T
//   Wcat[:,0:256] = W1 - W2 ; Wcat[:,256:512] = W2   (W_edge halves)
// grid: 2560 blocks x 256
// ---------------------------------------------------------------------------
__global__ __launch_bounds__(256) void prep_weights_kernel(
    const float* __restrict__ Wd, const float* __restrict__ We,
    const float* __restrict__ Wu,
    __hip_bfloat16* __restrict__ Wdt, __hip_bfloat16* __restrict__ Wct,
    __hip_bfloat16* __restrict__ Wut)
{
    int blk = blockIdx.x;
    if (blk < 1024) {                       // Wdt: 256x1024
        int i = blk * 256 + threadIdx.x;
        int p = i >> 10, d = i & 1023;
        Wdt[i] = __float2bfloat16(Wd[d * 256 + p]);
    } else if (blk < 1536) {                // Wct: 512x256
        int i = (blk - 1024) * 256 + threadIdx.x;
        int n = i >> 8, d = i & 255;
        float v = (n < 256) ? (We[d * 256 + n] - We[(256 + d) * 256 + n])
                            : We[(256 + d) * 256 + (n - 256)];
        Wct[i] = __float2bfloat16(v);
    } else {                                // Wut: 1024x256
        int i = (blk - 1536) * 256 + threadIdx.x;
        int dd = i >> 8, p = i & 255;
        Wut[i] = __float2bfloat16(Wu[p * 1024 + dd]);
    }
}

// ---------------------------------------------------------------------------
// MFMA bf16 GEMM: C = op(A[MxK] @ Bt[NxK]^T (+bias) (+src))
// 128x128 tile, BK=32, 4 waves (2x2), each wave 64x64 = 4x4 frags of 16x16.
// AFP32: A is fp32 in global; reg-stage + convert + ds_write (fuses the cast).
// ---------------------------------------------------------------------------
template<bool RELU, bool BIAS, bool ADDSRC, bool OUTBF16, bool AFP32>
__global__ __launch_bounds__(256) void gemm_mfma_kernel(
    const void* __restrict__ A,              // [M][K] bf16 (or fp32 if AFP32)
    const __hip_bfloat16* __restrict__ Bt,   // [N][K]  (B transposed)
    const float* __restrict__ bias,          // [N] or null
    const float* __restrict__ src,           // [M][N] fp32 or null
    void* __restrict__ Cout,                 // bf16 or fp32 [M][N]
    int M, int N, int K)
{
    __shared__ __align__(16) __hip_bfloat16 As[128 * 32];
    __shared__ __align__(16) __hip_bfloat16 Bs[128 * 32];

    const __hip_bfloat16* Ah = (const __hip_bfloat16*)A;
    const float*          Af = (const float*)A;

    const int tid  = threadIdx.x;
    const int lane = tid & 63;
    const int wave = tid >> 6;              // 0..3
    const int wr = wave >> 1, wc = wave & 1;
    const int row0 = blockIdx.y * 128;
    const int col0 = blockIdx.x * 128;

    const int g  = lane >> 4;               // k-group 0..3
    const int lr = lane & 15;

    // staging geometry: chunk c covers LDS bytes [c*1024, c*1024+1024)
    const int srow = (lane >> 2);
    const int scol = (lane & 3) * 8;

    f32x4 acc[4][4];
    #pragma unroll
    for (int m = 0; m < 4; ++m)
        #pragma unroll
        for (int n = 0; n < 4; ++n)
            acc[m][n] = (f32x4){0.f, 0.f, 0.f, 0.f};

    for (int k0 = 0; k0 < K; k0 += 32) {
        float4 av[4];
        if (AFP32) {
            // issue A fp32 loads before the barrier (they don't touch LDS)
            #pragma unroll
            for (int q = 0; q < 4; ++q) {
                int li = q * 256 + tid;     // li>>3 = row(0..127), li&7 = colgrp
                av[q] = *reinterpret_cast<const float4*>(
                    &Af[(long)(row0 + (li >> 3)) * K + k0 + (li & 7) * 4]);
            }
        }
        __syncthreads();   // prior iter's LDS reads complete before overwrite
        #pragma unroll
        for (int r = 0; r < 2; ++r) {
            const int c = r * 4 + wave;                 // 0..7, wave-uniform
            const int arow = c * 16 + srow;
            if (!AFP32)
                async_copy16(Ah + (row0 + arow) * (long)K + k0 + scol, As + c * 512);
            async_copy16(Bt + (col0 + arow) * (long)K + k0 + scol, Bs + c * 512);
        }
        if (AFP32) {
            #pragma unroll
            for (int q = 0; q < 4; ++q) {
                int li = q * 256 + tid;
                __hip_bfloat16 h0 = __float2bfloat16(av[q].x);
                __hip_bfloat16 h1 = __float2bfloat16(av[q].y);
                __hip_bfloat16 h2 = __float2bfloat16(av[q].z);
                __hip_bfloat16 h3 = __float2bfloat16(av[q].w);
                ushort4 o;
                o.x = *reinterpret_cast<unsigned short*>(&h0);
                o.y = *reinterpret_cast<unsigned short*>(&h1);
                o.z = *reinterpret_cast<unsigned short*>(&h2);
                o.w = *reinterpret_cast<unsigned short*>(&h3);
                *reinterpret_cast<ushort4*>(&As[(li >> 3) * 32 + (li & 7) * 4]) = o;
            }
        }
        __syncthreads();   // drains vmcnt(0)+lgkmcnt(0): staged data visible

        bf16x8 afr[4], bfr[4];
        #pragma unroll
        for (int m = 0; m < 4; ++m)
            afr[m] = *reinterpret_cast<const bf16x8*>(
                &As[(wr * 64 + m * 16 + lr) * 32 + g * 8]);
        #pragma unroll
        for (int n = 0; n < 4; ++n)
            bfr[n] = *reinterpret_cast<const bf16x8*>(
                &Bs[(wc * 64 + n * 16 + lr) * 32 + g * 8]);
        #pragma unroll
        for (int m = 0; m < 4; ++m)
            #pragma unroll
            for (int n = 0; n < 4; ++n)
                acc[m][n] = __builtin_amdgcn_mfma_f32_16x16x32_bf16(
                    afr[m], bfr[n], acc[m][n], 0, 0, 0);
    }

    // epilogue: C/D layout col=lane&15, row=(lane>>4)*4+j   [m89-verified]
    const int orow = row0 + wr * 64;
    const int ocol = col0 + wc * 64;
    #pragma unroll
    for (int m = 0; m < 4; ++m) {
        #pragma unroll
        for (int n = 0; n < 4; ++n) {
            const int gc = ocol + n * 16 + lr;
            const float bv = BIAS ? bias[gc] : 0.f;
            #pragma unroll
            for (int j = 0; j < 4; ++j) {
                const int gr = orow + m * 16 + g * 4 + j;
                float v = acc[m][n][j] + bv;
                if (ADDSRC) v += src[(long)gr * N + gc];
                if (RELU)   v = fmaxf(v, 0.f);
                if (OUTBF16)
                    reinterpret_cast<__hip_bfloat16*>(Cout)[(long)gr * N + gc] =
                        __float2bfloat16(v);
                else
                    reinterpret_cast<float*>(Cout)[(long)gr * N + gc] = v;
            }
        }
    }
}

// ---------------------------------------------------------------------------
// KNN v2: 2 rows per wave (32 lanes/row), 32 candidates per lane.
// Pack (fp32 distance bits << 32) | index as a non-negative double:
// f64 ordering == (distance, index) lexicographic ordering; ties -> lower
// index (matches lax.top_k). In-lane bitonic sort-32 (registers, static idx),
// then 16 extraction rounds: branchless two-phase u32 butterfly over xor
// offsets 1..16 (stays within each 32-lane half) + static shift on owner.
// ---------------------------------------------------------------------------
__global__ __launch_bounds__(256) void knn_kernel(
    const float* __restrict__ points, int* __restrict__ idx_out)
{
    __shared__ float px[NN], py[NN], pz[NN], psq[NN];
    const int b = blockIdx.x;
    const int tid = threadIdx.x;
    const float* P = points + (long)b * NN * 3;
    for (int i = tid; i < NN; i += 256) {
        float x = P[i * 3 + 0], y = P[i * 3 + 1], z = P[i * 3 + 2];
        px[i] = x; py[i] = y; pz[i] = z;
        psq[i] = x * x + y * y + z * z;
    }
    __syncthreads();

    const int wave = tid >> 6, lane = tid & 63;
    const int half = lane >> 5, r = lane & 31;
    const int n = blockIdx.y * 8 + wave * 2 + half;
    const float xn = px[n], yn = py[n], zn = pz[n], sqn = psq[n];

    double pk[32];
    #pragma unroll
    for (int j = 0; j < 32; ++j) {
        int m = r + 32 * j;
        float dot = xn * px[m] + yn * py[m] + zn * pz[m];
        float d = (sqn + psq[m]) - 2.0f * dot;   // same formula as rounds 1-2
        d = fmaxf(d, 0.0f);                      // only self can be -eps
        unsigned long long u =
            ((unsigned long long)__float_as_uint(d) << 32) | (unsigned)m;
        pk[j] = __longlong_as_double((long long)u);
    }

    // bitonic sort-32 ascending (all indices compile-time -> registers)
    #pragma unroll
    for (int k = 2; k <= 32; k <<= 1) {
        #pragma unroll
        for (int j = k >> 1; j > 0; j >>= 1) {
            #pragma unroll
            for (int i = 0; i < 32; ++i) {
                int ixj = i ^ j;
                if (ixj > i) {
                    double a = pk[i], c = pk[ixj];
                    double lo_ = fmin(a, c), hi_ = fmax(a, c);
                    if ((i & k) == 0) { pk[i] = lo_; pk[ixj] = hi_; }
                    else              { pk[i] = hi_; pk[ixj] = lo_; }
                }
            }
        }
    }

    double lm = pk[0];
    int myidx = 0;
    for (int it = 0; it < 16; ++it) {
        unsigned hi = (unsigned)__double2hiint(lm);   // distance bits
        unsigned lo = (unsigned)__double2loint(lm);   // candidate index
        unsigned wh = hi;
        #pragma unroll
        for (int off = 1; off <= 16; off <<= 1) {
            unsigned o = (unsigned)__shfl_xor((int)wh, off);
            wh = (o < wh) ? o : wh;
        }
        unsigned lc = (hi == wh) ? lo : 0xFFFFFFFFu;
        unsigned wl = lc;
        #pragma unroll
        for (int off = 1; off <= 16; off <<= 1) {
            unsigned o = (unsigned)__shfl_xor((int)wl, off);
            wl = (o < wl) ? o : wl;
        }
        if (r == it) myidx = (int)wl;
        if ((hi == wh) && (lo == wl)) {   // unique owner in this half
            // pop head: only first 17 slots can ever surface (<=16 pops total)
            #pragma unroll
            for (int j = 0; j < 16; ++j) pk[j] = pk[j + 1];
            lm = pk[0];
        }
    }
    if (r < 16)
        idx_out[((long)b * NN + n) * KK + r] = myidx;
}

// ---------------------------------------------------------------------------
// Gather + max/min over K + BN + ReLU -> local (bf16), vectorized ushort8.
// 32 threads per row, 8 rows per block.
// local[p] = relu( s*(c + be + (s>=0 ? max_k n : min_k n)) + t )
// ---------------------------------------------------------------------------
__global__ __launch_bounds__(256) void edge_max_kernel(
    const __hip_bfloat16* __restrict__ cn,   // MROWS x 512 bf16: [c | n]
    const int*   __restrict__ idx,           // MROWS x 16
    const float* __restrict__ b_edge,
    const float* __restrict__ gamma, const float* __restrict__ beta,
    const float* __restrict__ mean,  const float* __restrict__ var,
    __hip_bfloat16* __restrict__ local)
{
    const int tid  = threadIdx.x;
    const int rsub = tid >> 5;               // 0..7
    const int t    = tid & 31;               // channel group
    const long row = (long)blockIdx.x * 8 + rsub;
    const long bbase = (row >> 10) << 10;
    const int c0 = t * 8;

    __shared__ int sidx[8][KK];
    if (tid < 128)
        sidx[tid >> 4][tid & 15] =
            idx[((long)blockIdx.x * 8 + (tid >> 4)) * KK + (tid & 15)];
    __syncthreads();

    float mx[8], mn[8];
    #pragma unroll
    for (int e = 0; e < 8; ++e) { mx[e] = -3.0e38f; mn[e] = 3.0e38f; }

    #pragma unroll
    for (int k = 0; k < KK; ++k) {
        u16x8 v = *reinterpret_cast<const u16x8*>(
            cn + (bbase + sidx[rsub][k]) * 512 + 256 + c0);
        #pragma unroll
        for (int e = 0; e < 8; ++e) {
            float f = __uint_as_float(((unsigned)v[e]) << 16);
            mx[e] = fmaxf(mx[e], f);
            mn[e] = fminf(mn[e], f);
        }
    }

    u16x8 cv = *reinterpret_cast<const u16x8*>(cn + row * 512 + c0);
    u16x8 o;
    #pragma unroll
    for (int e = 0; e < 8; ++e) {
        const int c = c0 + e;
        float s  = gamma[c] * rsqrtf(var[c] + 1e-5f);
        float tt = beta[c] - mean[c] * s;
        float cf = __uint_as_float(((unsigned)cv[e]) << 16);
        float nsel = (s >= 0.f) ? mx[e] : mn[e];
        float vr = fmaxf(0.f, s * (cf + b_edge[c] + nsel) + tt);
        __hip_bfloat16 h = __float2bfloat16(vr);
        o[e] = *reinterpret_cast<unsigned short*>(&h);
    }
    *reinterpret_cast<u16x8*>(local + row * 256 + c0) = o;
}

// ---------------------------------------------------------------------------
extern "C" void kernel_launch(void* const* d_in, const int* in_sizes, int n_in,
                              void* d_out, int out_size, void* d_ws, size_t ws_size,
                              hipStream_t stream)
{
    const float* points   = (const float*)d_in[0];
    const float* features = (const float*)d_in[1];
    const float* W_down   = (const float*)d_in[2];
    const float* b_down   = (const float*)d_in[3];
    const float* W_edge   = (const float*)d_in[4];
    const float* b_edge   = (const float*)d_in[5];
    const float* bn_gamma = (const float*)d_in[6];
    const float* bn_beta  = (const float*)d_in[7];
    const float* bn_mean  = (const float*)d_in[8];
    const float* bn_var   = (const float*)d_in[9];
    const float* W_up     = (const float*)d_in[10];
    const float* b_up     = (const float*)d_in[11];
    float* out = (float*)d_out;

    // workspace layout
    char* w = (char*)d_ws;
    __hip_bfloat16* cn        = (__hip_bfloat16*)w;                   // 16MB
    __hip_bfloat16* local     = (__hip_bfloat16*)(w + (16ul << 20));  //  8MB
    __hip_bfloat16* feats_low = (__hip_bfloat16*)(w + (24ul << 20));  //  8MB
    char* wtail = w + (32ul << 20);
    __hip_bfloat16* Wdt = (__hip_bfloat16*)wtail;                     // 512KB
    __hip_bfloat16* Wct = (__hip_bfloat16*)(wtail + 524288);          // 256KB
    __hip_bfloat16* Wut = (__hip_bfloat16*)(wtail + 524288 + 262144); // 512KB
    int* nidx = (int*)(wtail + 524288 + 262144 + 524288);             // 1MB

    // prep (fused) + knn
    prep_weights_kernel<<<2560, 256, 0, stream>>>(W_down, W_edge, W_up, Wdt, Wct, Wut);
    knn_kernel<<<dim3(BB, NN / 8), 256, 0, stream>>>(points, nidx);

    // GEMM1: feats_low = relu(features @ W_down + b_down)  [16384x256, K=1024]
    // fp32 A converted in-kernel (saves the standalone conversion pass)
    gemm_mfma_kernel<true, true, false, true, true><<<dim3(2, 128), 256, 0, stream>>>(
        features, Wdt, b_down, nullptr, feats_low, MROWS, 256, 1024);

    // GEMM2: cn = feats_low @ Wcat  [16384x512, K=256]
    gemm_mfma_kernel<false, false, false, true, false><<<dim3(4, 128), 256, 0, stream>>>(
        feats_low, Wct, nullptr, nullptr, cn, MROWS, 512, 256);

    // gather-max + BN + relu -> local (bf16)
    edge_max_kernel<<<MROWS / 8, 256, 0, stream>>>(
        cn, nidx, b_edge, bn_gamma, bn_beta, bn_mean, bn_var, local);

    // GEMM3: out = features + local @ W_up + b_up  [16384x1024, K=256]
    gemm_mfma_kernel<false, true, true, false, false><<<dim3(8, 128), 256, 0, stream>>>(
        local, Wut, b_up, features, out, MROWS, 1024, 256);
}